// Round 2
// baseline (6518.812 us; speedup 1.0000x reference)
//
#include <hip/hip_runtime.h>
#include <hip/hip_bf16.h>
#include <cstdint>
#include <cstddef>

// Problem constants
#define NT   250000      // total nodes
#define NUU  200000      // users
#define NPP  50000       // products
#define EG   500000      // directed edges
#define E2   1000000     // doubled (undirected)
#define HD   128
#define NBLK_SCAN 977    // ceil(NT/256)

// Workspace layout (bytes) — total 186,208,008
#define X_OFF    0ull            // X    [NT*HD]  bf16 = 64,000,000
#define R1_OFF   64000000ull     // raw1 [NT*HD]  bf16 = 64,000,000
#define R2_OFF   128000000ull    // raw2 [NUU*HD] bf16 = 51,200,000 (users only)
#define CNT_OFF  179200000ull    // cnt [NT] i32
#define FILL_OFF 180200000ull    // fill[NT] i32
#define STAT_OFF 181200000ull    // 1024 f32: stats1[256] | stats2[256] | ss1[256] | ss2[256]
#define RPTR_OFF 181204096ull    // row_ptr [NT+1] i32
#define BSUM_OFF 182204100ull    // block sums [977] i32
#define COL_OFF  182208008ull    // col [E2] i32
#define WS_NEED  186208008ull
#define ZERO_INTS 501024         // (cnt + fill + stats) bytes / 4

typedef __hip_bfloat16 bf16;

__global__ __launch_bounds__(256) void k_zero(int* __restrict__ p, int n) {
    for (int i = blockIdx.x * 256 + threadIdx.x; i < n; i += gridDim.x * 256) p[i] = 0;
}

// ---------------- CSR build ----------------
__global__ __launch_bounds__(256) void k_count(const int* __restrict__ ei, int* __restrict__ cnt) {
    for (int e = blockIdx.x * 256 + threadIdx.x; e < E2; e += gridDim.x * 256) {
        int d = (e < EG) ? ei[e + EG] : ei[e - EG];   // doubled edges: dst side
        atomicAdd(&cnt[d], 1);
    }
}

__global__ __launch_bounds__(256) void k_scan1(const int* __restrict__ cnt, int* __restrict__ bsum) {
    __shared__ int lds[256];
    int i = blockIdx.x * 256 + threadIdx.x;
    int v = (i < NT) ? cnt[i] : 0;
    lds[threadIdx.x] = v; __syncthreads();
    for (int s = 128; s > 0; s >>= 1) {
        if (threadIdx.x < s) lds[threadIdx.x] += lds[threadIdx.x + s];
        __syncthreads();
    }
    if (threadIdx.x == 0) bsum[blockIdx.x] = lds[0];
}

__global__ __launch_bounds__(1024) void k_scan2(int* __restrict__ bsum) {
    __shared__ int lds[1024];
    int i = threadIdx.x;
    int v = (i < NBLK_SCAN) ? bsum[i] : 0;
    lds[i] = v; __syncthreads();
    for (int off = 1; off < 1024; off <<= 1) {
        int t = (i >= off) ? lds[i - off] : 0;
        __syncthreads();
        lds[i] += t;
        __syncthreads();
    }
    if (i < NBLK_SCAN) bsum[i] = lds[i] - v;   // exclusive
}

__global__ __launch_bounds__(256) void k_scan3(const int* __restrict__ cnt, const int* __restrict__ bsum,
                                               int* __restrict__ rp) {
    __shared__ int lds[256];
    int i = blockIdx.x * 256 + threadIdx.x;
    int v = (i < NT) ? cnt[i] : 0;
    lds[threadIdx.x] = v; __syncthreads();
    for (int off = 1; off < 256; off <<= 1) {
        int t = (threadIdx.x >= off) ? lds[threadIdx.x - off] : 0;
        __syncthreads();
        lds[threadIdx.x] += t;
        __syncthreads();
    }
    if (i < NT) rp[i] = bsum[blockIdx.x] + lds[threadIdx.x] - v;
    if (i == 0 && blockIdx.x == 0) rp[NT] = E2;
}

__global__ __launch_bounds__(256) void k_fill(const int* __restrict__ ei, const int* __restrict__ rp,
                                              int* __restrict__ fill, int* __restrict__ col) {
    for (int e = blockIdx.x * 256 + threadIdx.x; e < E2; e += gridDim.x * 256) {
        int s = ei[e];                                 // src side is row e of flat [2E]
        int d = (e < EG) ? ei[e + EG] : ei[e - EG];
        int slot = rp[d] + atomicAdd(&fill[d], 1);
        col[slot] = s;
    }
}

// ---------------- Input projection: out = relu(in @ W^T + b), bf16 store ----------------
template<int D, int LDP>
__global__ __launch_bounds__(128) void k_proj(const float* __restrict__ in, const float* __restrict__ W,
                                              const float* __restrict__ bias, bf16* __restrict__ out,
                                              int nrows, int rowbase) {
    constexpr int RP = 4;
    __shared__ float lds[RP * LDP];
    int j = threadIdx.x;
    float w[D];
#pragma unroll
    for (int k = 0; k < D; k++) w[k] = W[j * D + k];
    float bj = bias[j];
    for (int r0 = blockIdx.x * RP; r0 < nrows; r0 += gridDim.x * RP) {
        int nr = min(RP, nrows - r0);
        __syncthreads();
        for (int i = j; i < nr * D; i += 128) {
            int r = i / D, k = i - r * D;
            lds[r * LDP + k] = in[(size_t)r0 * D + i];
        }
        __syncthreads();
        float acc[RP];
#pragma unroll
        for (int r = 0; r < RP; r++) {
            float a = 0.f;
#pragma unroll
            for (int k = 0; k < D; k++) a += lds[r * LDP + k] * w[k];
            acc[r] = a;
        }
        for (int r = 0; r < nr; r++)
            out[(size_t)(rowbase + r0 + r) * HD + j] = __float2bfloat16(fmaxf(acc[r] + bj, 0.f));
    }
}

// ---------------- Fused SAGE layer ----------------
// raw = mean_nb(f(hin)) @ Wl^T + bl + f(hin) @ Wr^T   (f = identity, or BN-scale+relu if NORM)
// block=256: threads [0,128) hold Wl rows (grp0), [128,256) hold Wr rows (grp1).
// Epilogue: per-column sum/sumsq into stats; store rows only below store_n.
template<bool NORM>
__global__ __launch_bounds__(256) void k_sage(const bf16* __restrict__ hin, const float* __restrict__ ss,
                                              const int* __restrict__ rp, const int* __restrict__ col,
                                              const float* __restrict__ Wl, const float* __restrict__ blv,
                                              const float* __restrict__ Wr,
                                              bf16* __restrict__ outp, float* __restrict__ stats,
                                              int store_n) {
    constexpr int RP = 4;
    __shared__ float mrow[RP][HD];
    __shared__ float hrow[RP][HD];
    __shared__ float part[RP][HD];
    int tid = threadIdx.x;
    int j = tid & (HD - 1);
    int grp = tid >> 7;
    const float* W = grp ? Wr : Wl;
    float w[HD];
#pragma unroll
    for (int k = 0; k < HD; k++) w[k] = W[j * HD + k];
    float bj = blv[j];
    float sj = 1.f, shj = 0.f;
    if constexpr (NORM) { sj = ss[j]; shj = ss[HD + j]; }
    float ls = 0.f, lss = 0.f;

    for (int n0 = blockIdx.x * RP; n0 < NT; n0 += gridDim.x * RP) {
        int nr = min(RP, NT - n0);
        __syncthreads();   // protect LDS reuse from previous iteration
        // Phase A: gather/mean + own row; each group handles RP/2 nodes
        for (int q = 0; q < RP / 2; q++) {
            int r = grp * (RP / 2) + q;
            if (r < nr) {
                int node = n0 + r;
                int s0 = rp[node], s1 = rp[node + 1];
                float a = 0.f;
                int p = s0;
                for (; p + 3 < s1; p += 4) {   // 4 independent loads in flight
                    int c0 = col[p], c1 = col[p + 1], c2 = col[p + 2], c3 = col[p + 3];
                    float v0 = __bfloat162float(hin[(size_t)c0 * HD + j]);
                    float v1 = __bfloat162float(hin[(size_t)c1 * HD + j]);
                    float v2 = __bfloat162float(hin[(size_t)c2 * HD + j]);
                    float v3 = __bfloat162float(hin[(size_t)c3 * HD + j]);
                    if constexpr (NORM) {
                        v0 = fmaxf(fmaf(v0, sj, shj), 0.f); v1 = fmaxf(fmaf(v1, sj, shj), 0.f);
                        v2 = fmaxf(fmaf(v2, sj, shj), 0.f); v3 = fmaxf(fmaf(v3, sj, shj), 0.f);
                    }
                    a += v0 + v1 + v2 + v3;
                }
                for (; p < s1; p++) {
                    float v = __bfloat162float(hin[(size_t)col[p] * HD + j]);
                    if constexpr (NORM) v = fmaxf(fmaf(v, sj, shj), 0.f);
                    a += v;
                }
                float inv = 1.f / (float)max(s1 - s0, 1);
                float hv = __bfloat162float(hin[(size_t)node * HD + j]);
                if constexpr (NORM) hv = fmaxf(fmaf(hv, sj, shj), 0.f);
                mrow[r][j] = a * inv;
                hrow[r][j] = hv;
            }
        }
        __syncthreads();
        // Phase B: dot with register-resident W, row data broadcast from LDS
        float dacc[RP];
#pragma unroll
        for (int r = 0; r < RP; r++) {
            const float* rowd = grp ? hrow[r] : mrow[r];
            float a = 0.f;
#pragma unroll
            for (int k = 0; k < HD; k++) a += rowd[k] * w[k];
            dacc[r] = a;
        }
        if (grp) {
#pragma unroll
            for (int r = 0; r < RP; r++) part[r][j] = dacc[r];
        }
        __syncthreads();
        if (!grp) {
            for (int r = 0; r < nr; r++) {
                float o = dacc[r] + part[r][j] + bj;
                if (n0 + r < store_n) outp[(size_t)(n0 + r) * HD + j] = __float2bfloat16(o);
                ls += o; lss += o * o;
            }
        }
    }
    if (!grp) {
        atomicAdd(&stats[j], ls);
        atomicAdd(&stats[HD + j], lss);
    }
}

// ---------------- BN finalize: per-column scale/shift ----------------
__global__ void k_fin(const float* __restrict__ stats, const float* __restrict__ g,
                      const float* __restrict__ be, float* __restrict__ ss) {
    int j = threadIdx.x;
    float m = stats[j] * (1.f / (float)NT);
    float v = stats[HD + j] * (1.f / (float)NT) - m * m;
    float s = g[j] * rsqrtf(v + 1e-5f);
    ss[j] = s;
    ss[HD + j] = be[j] - m * s;
}

// ---------------- Final: out = (relu(bn(raw2)) + x)[:NU] @ Wout^T + bout ----------------
__global__ __launch_bounds__(256) void k_out(const bf16* __restrict__ r2, const float* __restrict__ ss,
                                             const bf16* __restrict__ x, const float* __restrict__ wout,
                                             const float* __restrict__ bout, float* __restrict__ outp) {
    int lane = threadIdx.x & 63;
    int wid = (blockIdx.x * blockDim.x + threadIdx.x) >> 6;
    int nwv = (gridDim.x * blockDim.x) >> 6;
    int j0 = lane * 2;
    float s0 = ss[j0],       s1 = ss[j0 + 1];
    float h0s = ss[HD + j0], h1s = ss[HD + j0 + 1];
    float w0 = wout[j0], w1 = wout[j0 + 1];
    float bo = bout[0];
    for (int r = wid; r < NUU; r += nwv) {
        float a0 = __bfloat162float(r2[(size_t)r * HD + j0]);
        float a1 = __bfloat162float(r2[(size_t)r * HD + j0 + 1]);
        float x0 = __bfloat162float(x[(size_t)r * HD + j0]);
        float x1 = __bfloat162float(x[(size_t)r * HD + j0 + 1]);
        float h0 = fmaxf(fmaf(a0, s0, h0s), 0.f) + x0;
        float h1 = fmaxf(fmaf(a1, s1, h1s), 0.f) + x1;
        float acc = h0 * w0 + h1 * w1;
#pragma unroll
        for (int off = 32; off; off >>= 1) acc += __shfl_down(acc, off);
        if (lane == 0) outp[r] = acc + bo;
    }
}

extern "C" void kernel_launch(void* const* d_in, const int* in_sizes, int n_in,
                              void* d_out, int out_size, void* d_ws, size_t ws_size,
                              hipStream_t stream) {
    const float* x_u = (const float*)d_in[0];
    const float* x_p = (const float*)d_in[1];
    const int*   ei  = (const int*)d_in[2];
    const float* W_u = (const float*)d_in[3];
    const float* b_u = (const float*)d_in[4];
    const float* W_p = (const float*)d_in[5];
    const float* b_p = (const float*)d_in[6];
    const float* W1l = (const float*)d_in[7];
    const float* b1l = (const float*)d_in[8];
    const float* W1r = (const float*)d_in[9];
    const float* g1  = (const float*)d_in[10];
    const float* be1 = (const float*)d_in[11];
    const float* W2l = (const float*)d_in[12];
    const float* b2l = (const float*)d_in[13];
    const float* W2r = (const float*)d_in[14];
    const float* g2  = (const float*)d_in[15];
    const float* be2 = (const float*)d_in[16];
    const float* Wout = (const float*)d_in[17];
    const float* bout = (const float*)d_in[18];

    float* out = (float*)d_out;

    // Workspace-size guard: if too small, emit zeros (clean diagnostic failure, no crash).
    if (ws_size < WS_NEED) {
        k_zero<<<512, 256, 0, stream>>>((int*)d_out, out_size);
        return;
    }

    char* ws = (char*)d_ws;
    bf16* X     = (bf16*)(ws + X_OFF);
    bf16* R1    = (bf16*)(ws + R1_OFF);
    bf16* R2    = (bf16*)(ws + R2_OFF);
    int* cnt    = (int*)(ws + CNT_OFF);
    int* fill   = (int*)(ws + FILL_OFF);
    float* stats = (float*)(ws + STAT_OFF);
    int* rp     = (int*)(ws + RPTR_OFF);
    int* bsum   = (int*)(ws + BSUM_OFF);
    int* col    = (int*)(ws + COL_OFF);

    // Zero cnt + fill + stats (capture-safe kernel, no memset)
    k_zero<<<512, 256, 0, stream>>>(cnt, ZERO_INTS);

    // CSR build
    k_count<<<1024, 256, 0, stream>>>(ei, cnt);
    k_scan1<<<NBLK_SCAN, 256, 0, stream>>>(cnt, bsum);
    k_scan2<<<1, 1024, 0, stream>>>(bsum);
    k_scan3<<<NBLK_SCAN, 256, 0, stream>>>(cnt, bsum, rp);
    k_fill<<<1024, 256, 0, stream>>>(ei, rp, fill, col);

    // Input projections -> X (bf16)
    k_proj<100, 104><<<2048, 128, 0, stream>>>(x_u, W_u, b_u, X, NUU, 0);
    k_proj<50, 56><<<1024, 128, 0, stream>>>(x_p, W_p, b_p, X, NPP, NUU);

    // Layer 1: X -> R1 (+stats1), store all NT rows
    k_sage<false><<<2048, 256, 0, stream>>>(X, nullptr, rp, col, W1l, b1l, W1r, R1, stats, NT);
    k_fin<<<1, 128, 0, stream>>>(stats, g1, be1, stats + 512);

    // Layer 2: f(R1) -> R2 (+stats2), BN1+relu on the fly, store only user rows
    k_sage<true><<<2048, 256, 0, stream>>>(R1, stats + 512, rp, col, W2l, b2l, W2r, R2, stats + 256, NUU);
    k_fin<<<1, 128, 0, stream>>>(stats + 256, g2, be2, stats + 768);

    // Output
    k_out<<<2048, 256, 0, stream>>>(R2, stats + 768, X, Wout, bout, out);
}

// Round 3
// 748.845 us; speedup vs baseline: 8.7052x; 8.7052x over previous
//
#include <hip/hip_runtime.h>
#include <hip/hip_bf16.h>
#include <cstdint>
#include <cstddef>

// Problem constants
#define NT   250000      // total nodes
#define NUU  200000      // users
#define NPP  50000       // products
#define EG   500000      // directed edges
#define E2   1000000     // doubled (undirected)
#define HD   128
#define NBLK_SCAN 977    // ceil(NT/256)

// Workspace layout (bytes) — total 185,451,728 (< proven-available 186,208,008)
#define X_OFF     0ull            // X  [NT*HD] bf16 = 64,000,000
#define R1_OFF    64000000ull     // R1 [NT*HD] bf16 = 64,000,000
#define R2_OFF    128000000ull    // R2 [NUU*HD] bf16 = 51,200,000
#define CNT_OFF   179200000ull    // cnt [NT] i32 (reused as fill) = 1,000,000
#define SPART_OFF 180200000ull    // stats partials 2 layers x 32 x 256 f32 = 65,536
#define SS_OFF    180265536ull    // ss1|ss2: 2 x 256 f32 = 2,048
#define RPTR_OFF  180267584ull    // row_ptr [NT+1] i32 = 1,000,004
#define BSUM_OFF  181267588ull    // block sums [977] i32 = 3,908
#define BMAT_OFF  181271504ull    // bf16 weights: L1[128][256] L2[128][256] PU[128][128] PP[128][64] = 180,224
#define COL_OFF   181451728ull    // col [E2] i32 = 4,000,000
#define WS_NEED   185451728ull

typedef __hip_bfloat16 bf16;
typedef __attribute__((ext_vector_type(8))) short short8v;
typedef __attribute__((ext_vector_type(4))) float f32x4;

__device__ inline float bflo(unsigned u) { return __builtin_bit_cast(float, u << 16); }
__device__ inline float bfhi(unsigned u) { return __builtin_bit_cast(float, u & 0xffff0000u); }
__device__ inline unsigned short f2bf(float f) { return __builtin_bit_cast(unsigned short, __float2bfloat16(f)); }

__global__ __launch_bounds__(256) void k_zero(int* __restrict__ p, int n) {
    for (int i = blockIdx.x * 256 + threadIdx.x; i < n; i += gridDim.x * 256) p[i] = 0;
}

// ---------------- CSR build ----------------
__global__ __launch_bounds__(256) void k_count(const int* __restrict__ ei, int* __restrict__ cnt) {
    for (int e = blockIdx.x * 256 + threadIdx.x; e < E2; e += gridDim.x * 256) {
        int d = (e < EG) ? ei[e + EG] : ei[e - EG];
        atomicAdd(&cnt[d], 1);
    }
}

__global__ __launch_bounds__(256) void k_scan1(const int* __restrict__ cnt, int* __restrict__ bsum) {
    __shared__ int lds[256];
    int i = blockIdx.x * 256 + threadIdx.x;
    int v = (i < NT) ? cnt[i] : 0;
    lds[threadIdx.x] = v; __syncthreads();
    for (int s = 128; s > 0; s >>= 1) {
        if (threadIdx.x < s) lds[threadIdx.x] += lds[threadIdx.x + s];
        __syncthreads();
    }
    if (threadIdx.x == 0) bsum[blockIdx.x] = lds[0];
}

__global__ __launch_bounds__(1024) void k_scan2(int* __restrict__ bsum) {
    __shared__ int lds[1024];
    int i = threadIdx.x;
    int v = (i < NBLK_SCAN) ? bsum[i] : 0;
    lds[i] = v; __syncthreads();
    for (int off = 1; off < 1024; off <<= 1) {
        int t = (i >= off) ? lds[i - off] : 0;
        __syncthreads();
        lds[i] += t;
        __syncthreads();
    }
    if (i < NBLK_SCAN) bsum[i] = lds[i] - v;   // exclusive
}

__global__ __launch_bounds__(256) void k_scan3(const int* __restrict__ cnt, const int* __restrict__ bsum,
                                               int* __restrict__ rp) {
    __shared__ int lds[256];
    int i = blockIdx.x * 256 + threadIdx.x;
    int v = (i < NT) ? cnt[i] : 0;
    lds[threadIdx.x] = v; __syncthreads();
    for (int off = 1; off < 256; off <<= 1) {
        int t = (threadIdx.x >= off) ? lds[threadIdx.x - off] : 0;
        __syncthreads();
        lds[threadIdx.x] += t;
        __syncthreads();
    }
    if (i < NT) rp[i] = bsum[blockIdx.x] + lds[threadIdx.x] - v;
    if (i == 0 && blockIdx.x == 0) rp[NT] = E2;
}

__global__ __launch_bounds__(256) void k_fill(const int* __restrict__ ei, const int* __restrict__ rp,
                                              int* __restrict__ fill, int* __restrict__ col) {
    for (int e = blockIdx.x * 256 + threadIdx.x; e < E2; e += gridDim.x * 256) {
        int s = ei[e];
        int d = (e < EG) ? ei[e + EG] : ei[e - EG];
        int slot = rp[d] + atomicAdd(&fill[d], 1);
        col[slot] = s;
    }
}

// ---------------- Weight conversion: fp32 -> bf16, stacked/padded ----------------
// B layout (bf16 elems): [0,65536) L1[out][k0..255] (k<128:Wl, else Wr)
//                        [65536,81920) PU[out][k0..127] (zero-pad k>=100)
//                        [81920,90112) PP[out][k0..63]  (zero-pad k>=50)
__global__ __launch_bounds__(256) void k_wcvt(const float* __restrict__ W1l, const float* __restrict__ W1r,
                                              const float* __restrict__ W2l, const float* __restrict__ W2r,
                                              const float* __restrict__ Wu, const float* __restrict__ Wp,
                                              bf16* __restrict__ B) {
    int i = blockIdx.x * 256 + threadIdx.x;
    if (i < 65536) {
        int layer = i >> 15, rem = i & 32767, o = rem >> 8, k = rem & 255;
        const float* W = layer ? ((k < 128) ? W2l : W2r) : ((k < 128) ? W1l : W1r);
        B[i] = __float2bfloat16(W[o * 128 + (k & 127)]);
    } else if (i < 81920) {
        int rem = i - 65536, o = rem >> 7, k = rem & 127;
        B[i] = __float2bfloat16((k < 100) ? Wu[o * 100 + k] : 0.f);
    } else if (i < 90112) {
        int rem = i - 81920, o = rem >> 6, k = rem & 63;
        B[i] = __float2bfloat16((k < 50) ? Wp[o * 50 + k] : 0.f);
    }
}

// ---------------- MFMA projection: X = relu(in @ Wp^T + b), K zero-padded ----------------
template<int DIN, int KPAD>
__global__ __launch_bounds__(256) void k_projm(const float* __restrict__ in, const bf16* __restrict__ Bp,
                                               const float* __restrict__ bias, bf16* __restrict__ outp,
                                               int nrows, int rowbase) {
    const int lane = threadIdx.x & 63;
    const int wid = threadIdx.x >> 6;
    const int wr = wid >> 1, wc = wid & 1;
    const int r15 = lane & 15, l4 = lane >> 4;
    const int tb = blockIdx.x * 128;
    constexpr int NKS = KPAD / 32;

    f32x4 acc[4][4] = {};
#pragma unroll
    for (int ks = 0; ks < NKS; ks++) {
        int kk = ks * 32 + l4 * 8;
        short8v a[4], b[4];
#pragma unroll
        for (int m = 0; m < 4; m++) {
            int r = tb + wr * 64 + m * 16 + r15;
            if (r > nrows - 1) r = nrows - 1;
            const float* src = in + (size_t)r * DIN + kk;
            short8v v;
#pragma unroll
            for (int j = 0; j < 8; j++) {
                float f = (kk + j < DIN) ? src[j] : 0.f;
                v[j] = (short)f2bf(f);
            }
            a[m] = v;
        }
#pragma unroll
        for (int n = 0; n < 4; n++) {
            int c = wc * 64 + n * 16 + r15;
            b[n] = *(const short8v*)(Bp + (size_t)c * KPAD + kk);
        }
#pragma unroll
        for (int m = 0; m < 4; m++)
#pragma unroll
            for (int n = 0; n < 4; n++)
                acc[m][n] = __builtin_amdgcn_mfma_f32_16x16x32_bf16(a[m], b[n], acc[m][n], 0, 0, 0);
    }
    float bcol[4];
#pragma unroll
    for (int n = 0; n < 4; n++) bcol[n] = bias[wc * 64 + n * 16 + r15];
#pragma unroll
    for (int m = 0; m < 4; m++)
#pragma unroll
        for (int n = 0; n < 4; n++)
#pragma unroll
            for (int g = 0; g < 4; g++) {
                int row = tb + wr * 64 + m * 16 + l4 * 4 + g;
                if (row < nrows) {
                    float v = fmaxf(acc[m][n][g] + bcol[n], 0.f);
                    outp[(size_t)(rowbase + row) * HD + wc * 64 + n * 16 + r15] = __float2bfloat16(v);
                }
            }
}

// ---------------- Fused SAGE layer: gather->LDS, then MFMA ----------------
// C[r][c] = sum_k meanNb(f(hin))[r][k]*Wl[c][k] + f(hin)[r][k]*Wr[c][k] + bl[c]
// f = identity (layer1) or relu(s*x+t) (layer2, per-column BN fold).
// K=256 view: ks 0..3 from LDS mean tile (XOR-swizzled), ks 4..7 from hin rows (norm on the fly).
template<bool NORM>
__global__ __launch_bounds__(256) void k_gemm(const bf16* __restrict__ hin, const float* __restrict__ ssv,
                                              const int* __restrict__ rp, const int* __restrict__ col,
                                              const bf16* __restrict__ Bmat, const float* __restrict__ blv,
                                              bf16* __restrict__ outp, float* __restrict__ spart,
                                              int store_n) {
    __shared__ unsigned int mrow[8192];   // 128 rows x 128 bf16, byte ^= (row&7)<<4 swizzle
    const int tid = threadIdx.x;
    const int lane = tid & 63;
    const int wid = tid >> 6;
    const int tb = blockIdx.x * 128;

    float gs0 = 1.f, gs1 = 1.f, gt0 = 0.f, gt1 = 0.f;
    if (NORM) {
        gs0 = ssv[2 * lane];      gs1 = ssv[2 * lane + 1];
        gt0 = ssv[HD + 2 * lane]; gt1 = ssv[HD + 2 * lane + 1];
    }

    // ---- Phase A: each wave gathers means for 32 nodes (dword = 2 bf16 per lane) ----
    for (int q = 0; q < 32; q++) {
        int nl = wid * 32 + q;
        int node = tb + nl; if (node > NT - 1) node = NT - 1;
        int s0 = rp[node], s1 = rp[node + 1];
        float a0 = 0.f, a1 = 0.f;
        int p = s0;
        for (; p + 3 < s1; p += 4) {   // 4 row-loads in flight
            int c0 = col[p], c1 = col[p + 1], c2 = col[p + 2], c3 = col[p + 3];
            unsigned u0 = *(const unsigned*)(hin + (size_t)c0 * HD + 2 * lane);
            unsigned u1 = *(const unsigned*)(hin + (size_t)c1 * HD + 2 * lane);
            unsigned u2 = *(const unsigned*)(hin + (size_t)c2 * HD + 2 * lane);
            unsigned u3 = *(const unsigned*)(hin + (size_t)c3 * HD + 2 * lane);
            float v0l = bflo(u0), v0h = bfhi(u0), v1l = bflo(u1), v1h = bfhi(u1);
            float v2l = bflo(u2), v2h = bfhi(u2), v3l = bflo(u3), v3h = bfhi(u3);
            if (NORM) {
                v0l = fmaxf(fmaf(v0l, gs0, gt0), 0.f); v0h = fmaxf(fmaf(v0h, gs1, gt1), 0.f);
                v1l = fmaxf(fmaf(v1l, gs0, gt0), 0.f); v1h = fmaxf(fmaf(v1h, gs1, gt1), 0.f);
                v2l = fmaxf(fmaf(v2l, gs0, gt0), 0.f); v2h = fmaxf(fmaf(v2h, gs1, gt1), 0.f);
                v3l = fmaxf(fmaf(v3l, gs0, gt0), 0.f); v3h = fmaxf(fmaf(v3h, gs1, gt1), 0.f);
            }
            a0 += v0l + v1l + v2l + v3l;
            a1 += v0h + v1h + v2h + v3h;
        }
        for (; p < s1; p++) {
            unsigned u = *(const unsigned*)(hin + (size_t)col[p] * HD + 2 * lane);
            float vl = bflo(u), vh = bfhi(u);
            if (NORM) { vl = fmaxf(fmaf(vl, gs0, gt0), 0.f); vh = fmaxf(fmaf(vh, gs1, gt1), 0.f); }
            a0 += vl; a1 += vh;
        }
        float inv = 1.f / (float)max(s1 - s0, 1);
        unsigned w = (unsigned)f2bf(a0 * inv) | ((unsigned)f2bf(a1 * inv) << 16);
        int byte = (nl * 256 + lane * 4) ^ ((nl & 7) << 4);
        mrow[byte >> 2] = w;
    }
    __syncthreads();

    // ---- Phase B: MFMA over K=256 ----
    const int wr = wid >> 1, wc = wid & 1;
    const int r15 = lane & 15, l4 = lane >> 4;
    f32x4 acc[4][4] = {};
#pragma unroll
    for (int ks = 0; ks < 8; ks++) {
        short8v a[4], b[4];
        if (ks < 4) {
            int kb = ks * 64 + l4 * 16;          // byte offset of k-slice within row
#pragma unroll
            for (int m = 0; m < 4; m++) {
                int r = wr * 64 + m * 16 + r15;
                int byte = (r * 256 + kb) ^ ((r & 7) << 4);
                a[m] = *(const short8v*)((const char*)mrow + byte);
            }
        } else {
            int k2 = (ks - 4) * 32 + l4 * 8;
            float sv[8], tv[8];
            if (NORM) {
#pragma unroll
                for (int j = 0; j < 8; j++) { sv[j] = ssv[k2 + j]; tv[j] = ssv[HD + k2 + j]; }
            }
#pragma unroll
            for (int m = 0; m < 4; m++) {
                int r = tb + wr * 64 + m * 16 + r15; if (r > NT - 1) r = NT - 1;
                short8v v = *(const short8v*)(hin + (size_t)r * HD + k2);
                if (NORM) {
#pragma unroll
                    for (int j = 0; j < 8; j++) {
                        float f = __builtin_bit_cast(float, ((unsigned)(unsigned short)v[j]) << 16);
                        f = fmaxf(fmaf(f, sv[j], tv[j]), 0.f);
                        v[j] = (short)f2bf(f);
                    }
                }
                a[m] = v;
            }
        }
#pragma unroll
        for (int n = 0; n < 4; n++) {
            int c = wc * 64 + n * 16 + r15;
            b[n] = *(const short8v*)(Bmat + (size_t)c * 256 + ks * 32 + l4 * 8);
        }
#pragma unroll
        for (int m = 0; m < 4; m++)
#pragma unroll
            for (int n = 0; n < 4; n++)
                acc[m][n] = __builtin_amdgcn_mfma_f32_16x16x32_bf16(a[m], b[n], acc[m][n], 0, 0, 0);
    }

    // ---- Epilogue: bias, store, BN stats ----
    float bcol[4];
#pragma unroll
    for (int n = 0; n < 4; n++) bcol[n] = blv[wc * 64 + n * 16 + r15];
    float ls[4] = {0.f, 0.f, 0.f, 0.f}, lq[4] = {0.f, 0.f, 0.f, 0.f};
#pragma unroll
    for (int m = 0; m < 4; m++)
#pragma unroll
        for (int n = 0; n < 4; n++)
#pragma unroll
            for (int g = 0; g < 4; g++) {
                int row = tb + wr * 64 + m * 16 + l4 * 4 + g;
                float v = acc[m][n][g] + bcol[n];
                if (row < NT) { ls[n] += v; lq[n] += v * v; }
                if (row < store_n)
                    outp[(size_t)row * HD + wc * 64 + n * 16 + r15] = __float2bfloat16(v);
            }
    int part = (blockIdx.x & 31) * 256;
#pragma unroll
    for (int n = 0; n < 4; n++) {
        float s = ls[n], q2 = lq[n];
        s  += __shfl_xor(s, 16);  s  += __shfl_xor(s, 32);
        q2 += __shfl_xor(q2, 16); q2 += __shfl_xor(q2, 32);
        if (l4 == 0) {
            int c = wc * 64 + n * 16 + r15;
            atomicAdd(&spart[part + c], s);
            atomicAdd(&spart[part + 128 + c], q2);
        }
    }
}

// ---------------- BN finalize: reduce 32 partials -> per-column scale/shift ----------------
__global__ void k_fin(const float* __restrict__ sp, const float* __restrict__ g,
                      const float* __restrict__ be, float* __restrict__ ssout) {
    int j = threadIdx.x;   // 128
    float m = 0.f, q = 0.f;
    for (int i = 0; i < 32; i++) { m += sp[i * 256 + j]; q += sp[i * 256 + 128 + j]; }
    m *= (1.f / (float)NT);
    q = q * (1.f / (float)NT) - m * m;
    float s = g[j] * rsqrtf(q + 1e-5f);
    ssout[j] = s;
    ssout[HD + j] = be[j] - m * s;
}

// ---------------- Final: out = (relu(bn(raw2)) + x)[:NU] @ Wout^T + bout ----------------
__global__ __launch_bounds__(256) void k_out(const bf16* __restrict__ r2, const float* __restrict__ ss,
                                             const bf16* __restrict__ x, const float* __restrict__ wout,
                                             const float* __restrict__ bout, float* __restrict__ outp) {
    int lane = threadIdx.x & 63;
    int wid = (blockIdx.x * blockDim.x + threadIdx.x) >> 6;
    int nwv = (gridDim.x * blockDim.x) >> 6;
    int j0 = lane * 2;
    float s0 = ss[j0],       s1 = ss[j0 + 1];
    float t0 = ss[HD + j0],  t1 = ss[HD + j0 + 1];
    float w0 = wout[j0], w1 = wout[j0 + 1];
    float bo = bout[0];
    for (int r = wid; r < NUU; r += nwv) {
        unsigned ua = *(const unsigned*)(r2 + (size_t)r * HD + j0);
        unsigned ux = *(const unsigned*)(x + (size_t)r * HD + j0);
        float h0 = fmaxf(fmaf(bflo(ua), s0, t0), 0.f) + bflo(ux);
        float h1 = fmaxf(fmaf(bfhi(ua), s1, t1), 0.f) + bfhi(ux);
        float acc = h0 * w0 + h1 * w1;
#pragma unroll
        for (int off = 32; off; off >>= 1) acc += __shfl_down(acc, off);
        if (lane == 0) outp[r] = acc + bo;
    }
}

extern "C" void kernel_launch(void* const* d_in, const int* in_sizes, int n_in,
                              void* d_out, int out_size, void* d_ws, size_t ws_size,
                              hipStream_t stream) {
    const float* x_u = (const float*)d_in[0];
    const float* x_p = (const float*)d_in[1];
    const int*   ei  = (const int*)d_in[2];
    const float* W_u = (const float*)d_in[3];
    const float* b_u = (const float*)d_in[4];
    const float* W_p = (const float*)d_in[5];
    const float* b_p = (const float*)d_in[6];
    const float* W1l = (const float*)d_in[7];
    const float* b1l = (const float*)d_in[8];
    const float* W1r = (const float*)d_in[9];
    const float* g1  = (const float*)d_in[10];
    const float* be1 = (const float*)d_in[11];
    const float* W2l = (const float*)d_in[12];
    const float* b2l = (const float*)d_in[13];
    const float* W2r = (const float*)d_in[14];
    const float* g2  = (const float*)d_in[15];
    const float* be2 = (const float*)d_in[16];
    const float* Wout = (const float*)d_in[17];
    const float* bout = (const float*)d_in[18];

    float* out = (float*)d_out;

    if (ws_size < WS_NEED) {   // diagnostic fallback (should not trigger: prev round proved >=186.2MB)
        k_zero<<<512, 256, 0, stream>>>((int*)d_out, out_size);
        return;
    }

    char* ws = (char*)d_ws;
    bf16* X      = (bf16*)(ws + X_OFF);
    bf16* R1     = (bf16*)(ws + R1_OFF);
    bf16* R2     = (bf16*)(ws + R2_OFF);
    int*  cnt    = (int*)(ws + CNT_OFF);
    float* spart = (float*)(ws + SPART_OFF);
    float* ssbuf = (float*)(ws + SS_OFF);
    int*  rp     = (int*)(ws + RPTR_OFF);
    int*  bsum   = (int*)(ws + BSUM_OFF);
    bf16* Bmat   = (bf16*)(ws + BMAT_OFF);
    int*  col    = (int*)(ws + COL_OFF);

    // Zero cnt + spart + ss (contiguous: 1,000,000 + 65,536 + 2,048 bytes = 266,896 ints)
    k_zero<<<1043, 256, 0, stream>>>(cnt, 266896);
    k_wcvt<<<352, 256, 0, stream>>>(W1l, W1r, W2l, W2r, W_u, W_p, Bmat);

    // CSR build
    k_count<<<1024, 256, 0, stream>>>(ei, cnt);
    k_scan1<<<NBLK_SCAN, 256, 0, stream>>>(cnt, bsum);
    k_scan2<<<1, 1024, 0, stream>>>(bsum);
    k_scan3<<<NBLK_SCAN, 256, 0, stream>>>(cnt, bsum, rp);
    k_zero<<<977, 256, 0, stream>>>(cnt, NT);          // reuse cnt as fill
    k_fill<<<1024, 256, 0, stream>>>(ei, rp, cnt, col);

    // Projections -> X (bf16), MFMA with zero-padded K
    k_projm<100, 128><<<1563, 256, 0, stream>>>(x_u, Bmat + 65536, b_u, X, NUU, 0);
    k_projm<50, 64><<<391, 256, 0, stream>>>(x_p, Bmat + 81920, b_p, X, NPP, NUU);

    // Layer 1: X -> R1 (+stats1)
    k_gemm<false><<<1954, 256, 0, stream>>>(X, nullptr, rp, col, Bmat, b1l, R1, spart, NT);
    k_fin<<<1, 128, 0, stream>>>(spart, g1, be1, ssbuf);

    // Layer 2: f(R1) -> R2 (+stats2), BN1+relu folded into gather and A2 loads
    k_gemm<true><<<1954, 256, 0, stream>>>(R1, ssbuf, rp, col, Bmat + 32768, b2l, R2, spart + 8192, NUU);
    k_fin<<<1, 128, 0, stream>>>(spart + 8192, g2, be2, ssbuf + 256);

    // Output
    k_out<<<2048, 256, 0, stream>>>(R2, ssbuf + 256, X, Wout, bout, out);
}

// Round 4
// 464.895 us; speedup vs baseline: 14.0221x; 1.6108x over previous
//
#include <hip/hip_runtime.h>
#include <hip/hip_bf16.h>
#include <cstdint>
#include <cstddef>

// Problem constants
#define NT   250000      // total nodes
#define NUU  200000      // users
#define NPP  50000       // products
#define EG   500000      // directed edges
#define E2   1000000     // doubled (undirected)
#define HD   128
#define NBLK_SCAN 977    // ceil(NT/256)

// Workspace layout (bytes) — total 185,451,728 (< proven-available 186,208,008)
#define X_OFF     0ull            // X  [NT*HD] bf16 = 64,000,000
#define R1_OFF    64000000ull     // R1 [NT*HD] bf16 = 64,000,000
#define R2_OFF    128000000ull    // R2 [NUU*HD] bf16 = 51,200,000
#define CNT_OFF   179200000ull    // cnt [NT] i32 (reused as fill) = 1,000,000
#define SPART_OFF 180200000ull    // stats partials 2 layers x 32 x 256 f32 = 65,536
#define SS_OFF    180265536ull    // ss1|ss2: 2 x 256 f32 = 2,048
#define RPTR_OFF  180267584ull    // row_ptr [NT+1] i32 = 1,000,004
#define BSUM_OFF  181267588ull    // block sums [977] i32 = 3,908
#define BMAT_OFF  181271504ull    // bf16 weights: L1[128][256] L2[128][256] PU[128][128] PP[128][64]
#define COL_OFF   181451728ull    // col [E2] i32 = 4,000,000
#define WS_NEED   185451728ull

typedef __hip_bfloat16 bf16;
typedef __attribute__((ext_vector_type(8))) short short8v;
typedef __attribute__((ext_vector_type(4))) float f32x4;

__device__ inline float bflo(unsigned u) { return __builtin_bit_cast(float, u << 16); }
__device__ inline float bfhi(unsigned u) { return __builtin_bit_cast(float, u & 0xffff0000u); }
__device__ inline float b2f(short s) { return __builtin_bit_cast(float, ((unsigned)(unsigned short)s) << 16); }
__device__ inline unsigned short f2bf(float f) { return __builtin_bit_cast(unsigned short, __float2bfloat16(f)); }

__global__ __launch_bounds__(256) void k_zero(int* __restrict__ p, int n) {
    for (int i = blockIdx.x * 256 + threadIdx.x; i < n; i += gridDim.x * 256) p[i] = 0;
}

// ---------------- CSR build ----------------
__global__ __launch_bounds__(256) void k_count(const int* __restrict__ ei, int* __restrict__ cnt) {
    for (int e = blockIdx.x * 256 + threadIdx.x; e < E2; e += gridDim.x * 256) {
        int d = (e < EG) ? ei[e + EG] : ei[e - EG];
        atomicAdd(&cnt[d], 1);
    }
}

__global__ __launch_bounds__(256) void k_scan1(const int* __restrict__ cnt, int* __restrict__ bsum) {
    __shared__ int lds[256];
    int i = blockIdx.x * 256 + threadIdx.x;
    int v = (i < NT) ? cnt[i] : 0;
    lds[threadIdx.x] = v; __syncthreads();
    for (int s = 128; s > 0; s >>= 1) {
        if (threadIdx.x < s) lds[threadIdx.x] += lds[threadIdx.x + s];
        __syncthreads();
    }
    if (threadIdx.x == 0) bsum[blockIdx.x] = lds[0];
}

__global__ __launch_bounds__(1024) void k_scan2(int* __restrict__ bsum) {
    __shared__ int lds[1024];
    int i = threadIdx.x;
    int v = (i < NBLK_SCAN) ? bsum[i] : 0;
    lds[i] = v; __syncthreads();
    for (int off = 1; off < 1024; off <<= 1) {
        int t = (i >= off) ? lds[i - off] : 0;
        __syncthreads();
        lds[i] += t;
        __syncthreads();
    }
    if (i < NBLK_SCAN) bsum[i] = lds[i] - v;   // exclusive
}

__global__ __launch_bounds__(256) void k_scan3(const int* __restrict__ cnt, const int* __restrict__ bsum,
                                               int* __restrict__ rp) {
    __shared__ int lds[256];
    int i = blockIdx.x * 256 + threadIdx.x;
    int v = (i < NT) ? cnt[i] : 0;
    lds[threadIdx.x] = v; __syncthreads();
    for (int off = 1; off < 256; off <<= 1) {
        int t = (threadIdx.x >= off) ? lds[threadIdx.x - off] : 0;
        __syncthreads();
        lds[threadIdx.x] += t;
        __syncthreads();
    }
    if (i < NT) rp[i] = bsum[blockIdx.x] + lds[threadIdx.x] - v;
    if (i == 0 && blockIdx.x == 0) rp[NT] = E2;
}

__global__ __launch_bounds__(256) void k_fill(const int* __restrict__ ei, const int* __restrict__ rp,
                                              int* __restrict__ fill, int* __restrict__ col) {
    for (int e = blockIdx.x * 256 + threadIdx.x; e < E2; e += gridDim.x * 256) {
        int s = ei[e];
        int d = (e < EG) ? ei[e + EG] : ei[e - EG];
        int slot = rp[d] + atomicAdd(&fill[d], 1);
        col[slot] = s;
    }
}

// ---------------- Weight conversion: fp32 -> bf16, stacked/padded ----------------
__global__ __launch_bounds__(256) void k_wcvt(const float* __restrict__ W1l, const float* __restrict__ W1r,
                                              const float* __restrict__ W2l, const float* __restrict__ W2r,
                                              const float* __restrict__ Wu, const float* __restrict__ Wp,
                                              bf16* __restrict__ B) {
    int i = blockIdx.x * 256 + threadIdx.x;
    if (i < 65536) {
        int layer = i >> 15, rem = i & 32767, o = rem >> 8, k = rem & 255;
        const float* W = layer ? ((k < 128) ? W2l : W2r) : ((k < 128) ? W1l : W1r);
        B[i] = __float2bfloat16(W[o * 128 + (k & 127)]);
    } else if (i < 81920) {
        int rem = i - 65536, o = rem >> 7, k = rem & 127;
        B[i] = __float2bfloat16((k < 100) ? Wu[o * 100 + k] : 0.f);
    } else if (i < 90112) {
        int rem = i - 81920, o = rem >> 6, k = rem & 63;
        B[i] = __float2bfloat16((k < 50) ? Wp[o * 50 + k] : 0.f);
    }
}

// ---------------- MFMA projection: X = relu(in @ Wp^T + b), K zero-padded ----------------
template<int DIN, int KPAD>
__global__ __launch_bounds__(256) void k_projm(const float* __restrict__ in, const bf16* __restrict__ Bp,
                                               const float* __restrict__ bias, bf16* __restrict__ outp,
                                               int nrows, int rowbase) {
    const int lane = threadIdx.x & 63;
    const int wid = threadIdx.x >> 6;
    const int wr = wid >> 1, wc = wid & 1;
    const int r15 = lane & 15, l4 = lane >> 4;
    const int tb = blockIdx.x * 128;
    constexpr int NKS = KPAD / 32;

    f32x4 acc[4][4] = {};
#pragma unroll
    for (int ks = 0; ks < NKS; ks++) {
        int kk = ks * 32 + l4 * 8;
        short8v a[4], b[4];
#pragma unroll
        for (int m = 0; m < 4; m++) {
            int r = tb + wr * 64 + m * 16 + r15;
            if (r > nrows - 1) r = nrows - 1;
            const float* src = in + (size_t)r * DIN + kk;
            short8v v;
            if constexpr (DIN >= 32 * (1) && true) {
                if (ks * 32 + 32 <= DIN) {   // compile-time per unrolled ks: fully in-bounds
                    const float2* s2 = (const float2*)src;
                    float2 f0 = s2[0], f1 = s2[1], f2 = s2[2], f3 = s2[3];
                    v[0] = (short)f2bf(f0.x); v[1] = (short)f2bf(f0.y);
                    v[2] = (short)f2bf(f1.x); v[3] = (short)f2bf(f1.y);
                    v[4] = (short)f2bf(f2.x); v[5] = (short)f2bf(f2.y);
                    v[6] = (short)f2bf(f3.x); v[7] = (short)f2bf(f3.y);
                } else {
#pragma unroll
                    for (int j = 0; j < 8; j++) {
                        float f = (kk + j < DIN) ? src[j] : 0.f;
                        v[j] = (short)f2bf(f);
                    }
                }
            }
            a[m] = v;
        }
#pragma unroll
        for (int n = 0; n < 4; n++) {
            int c = wc * 64 + n * 16 + r15;
            b[n] = *(const short8v*)(Bp + (size_t)c * KPAD + kk);
        }
#pragma unroll
        for (int m = 0; m < 4; m++)
#pragma unroll
            for (int n = 0; n < 4; n++)
                acc[m][n] = __builtin_amdgcn_mfma_f32_16x16x32_bf16(a[m], b[n], acc[m][n], 0, 0, 0);
    }
    float bcol[4];
#pragma unroll
    for (int n = 0; n < 4; n++) bcol[n] = bias[wc * 64 + n * 16 + r15];
#pragma unroll
    for (int m = 0; m < 4; m++)
#pragma unroll
        for (int n = 0; n < 4; n++)
#pragma unroll
            for (int g = 0; g < 4; g++) {
                int row = tb + wr * 64 + m * 16 + l4 * 4 + g;
                if (row < nrows) {
                    float v = fmaxf(acc[m][n][g] + bcol[n], 0.f);
                    outp[(size_t)(rowbase + row) * HD + wc * 64 + n * 16 + r15] = __float2bfloat16(v);
                }
            }
}

// ---------------- Fused SAGE layer: MLP-optimized gather -> LDS, then MFMA ----------------
// Phase A: 4 nodes per wave in parallel (16-lane groups, 16B/lane row loads),
//          masked 4-wide edge batches (always 4 loads in flight), rp prefetched via shfl.
// Phase B: K=256 MFMA; ks 0..3 from swizzled LDS mean tile, ks 4..7 own rows (norm on the fly).
template<bool NORM>
__global__ __launch_bounds__(256) void k_gemm(const bf16* __restrict__ hin, const float* __restrict__ ssv,
                                              const int* __restrict__ rp, const int* __restrict__ col,
                                              const bf16* __restrict__ Bmat, const float* __restrict__ blv,
                                              bf16* __restrict__ outp, float* __restrict__ spart,
                                              int store_n) {
    __shared__ unsigned int mrow[8192];   // 128 rows x 128 bf16, byte ^= (row&7)<<4 swizzle
    const int tid = threadIdx.x;
    const int lane = tid & 63;
    const int wid = tid >> 6;
    const int g16 = lane >> 4, l16 = lane & 15;
    const int tb = blockIdx.x * 128;
    const int wnb = wid * 32;             // wave's node-local base

    // Per-lane BN fold constants for features f0..f0+7 (gather path)
    float sv[8], tv[8];
    if (NORM) {
        int f0 = l16 * 8;
#pragma unroll
        for (int j = 0; j < 8; j++) { sv[j] = ssv[f0 + j]; tv[j] = ssv[HD + f0 + j]; }
    }

    // Prefetch rp for the wave's 32 nodes (+1) in one coalesced load
    int rpv = 0;
    if (lane <= 32) {
        int idx = tb + wnb + lane;
        rpv = rp[min(idx, NT)];
    }

    // ---- Phase A: 8 rounds x 4 nodes (one per 16-lane group) ----
    for (int t = 0; t < 8; t++) {
        int nl = wnb + t * 4 + g16;       // node-local row in tile
        int node = tb + nl;
        int s0 = __shfl(rpv, t * 4 + g16);
        int s1 = __shfl(rpv, t * 4 + g16 + 1);
        if (node >= NT) { s0 = 0; s1 = 0; }
        float a[8] = {0.f, 0.f, 0.f, 0.f, 0.f, 0.f, 0.f, 0.f};
        for (int p = s0; p < s1; p += 4) {
            int c0 = col[p];
            int c1 = col[min(p + 1, s1 - 1)];
            int c2 = col[min(p + 2, s1 - 1)];
            int c3 = col[min(p + 3, s1 - 1)];
            short8v u0 = *(const short8v*)(hin + (size_t)c0 * HD + l16 * 8);
            short8v u1 = *(const short8v*)(hin + (size_t)c1 * HD + l16 * 8);
            short8v u2 = *(const short8v*)(hin + (size_t)c2 * HD + l16 * 8);
            short8v u3 = *(const short8v*)(hin + (size_t)c3 * HD + l16 * 8);
            float m1 = (p + 1 < s1) ? 1.f : 0.f;
            float m2 = (p + 2 < s1) ? 1.f : 0.f;
            float m3 = (p + 3 < s1) ? 1.f : 0.f;
#pragma unroll
            for (int j = 0; j < 8; j++) {
                float v0 = b2f(u0[j]), v1 = b2f(u1[j]), v2 = b2f(u2[j]), v3 = b2f(u3[j]);
                if (NORM) {
                    v0 = fmaxf(fmaf(v0, sv[j], tv[j]), 0.f);
                    v1 = fmaxf(fmaf(v1, sv[j], tv[j]), 0.f);
                    v2 = fmaxf(fmaf(v2, sv[j], tv[j]), 0.f);
                    v3 = fmaxf(fmaf(v3, sv[j], tv[j]), 0.f);
                }
                a[j] += v0 + m1 * v1 + m2 * v2 + m3 * v3;
            }
        }
        float inv = 1.f / (float)max(s1 - s0, 1);
        short8v w;
#pragma unroll
        for (int j = 0; j < 8; j++) w[j] = (short)f2bf(a[j] * inv);
        int byte = (nl * 256 + l16 * 16) ^ ((nl & 7) << 4);
        *(short8v*)((char*)mrow + byte) = w;
    }
    __syncthreads();

    // ---- Phase B: MFMA over K=256 ----
    const int wr = wid >> 1, wc = wid & 1;
    const int r15 = lane & 15, l4 = lane >> 4;
    f32x4 acc[4][4] = {};
#pragma unroll
    for (int ks = 0; ks < 8; ks++) {
        short8v a[4], b[4];
        if (ks < 4) {
            int kb = ks * 64 + l4 * 16;          // byte offset of k-slice within row
#pragma unroll
            for (int m = 0; m < 4; m++) {
                int r = wr * 64 + m * 16 + r15;
                int byte = (r * 256 + kb) ^ ((r & 7) << 4);
                a[m] = *(const short8v*)((const char*)mrow + byte);
            }
        } else {
            int k2 = (ks - 4) * 32 + l4 * 8;
            float sv2[8], tv2[8];
            if (NORM) {
#pragma unroll
                for (int j = 0; j < 8; j++) { sv2[j] = ssv[k2 + j]; tv2[j] = ssv[HD + k2 + j]; }
            }
#pragma unroll
            for (int m = 0; m < 4; m++) {
                int r = tb + wr * 64 + m * 16 + r15; if (r > NT - 1) r = NT - 1;
                short8v v = *(const short8v*)(hin + (size_t)r * HD + k2);
                if (NORM) {
#pragma unroll
                    for (int j = 0; j < 8; j++) {
                        float f = b2f(v[j]);
                        f = fmaxf(fmaf(f, sv2[j], tv2[j]), 0.f);
                        v[j] = (short)f2bf(f);
                    }
                }
                a[m] = v;
            }
        }
#pragma unroll
        for (int n = 0; n < 4; n++) {
            int c = wc * 64 + n * 16 + r15;
            b[n] = *(const short8v*)(Bmat + (size_t)c * 256 + ks * 32 + l4 * 8);
        }
#pragma unroll
        for (int m = 0; m < 4; m++)
#pragma unroll
            for (int n = 0; n < 4; n++)
                acc[m][n] = __builtin_amdgcn_mfma_f32_16x16x32_bf16(a[m], b[n], acc[m][n], 0, 0, 0);
    }

    // ---- Epilogue: bias, store, BN stats ----
    float bcol[4];
#pragma unroll
    for (int n = 0; n < 4; n++) bcol[n] = blv[wc * 64 + n * 16 + r15];
    float ls[4] = {0.f, 0.f, 0.f, 0.f}, lq[4] = {0.f, 0.f, 0.f, 0.f};
#pragma unroll
    for (int m = 0; m < 4; m++)
#pragma unroll
        for (int n = 0; n < 4; n++)
#pragma unroll
            for (int g = 0; g < 4; g++) {
                int row = tb + wr * 64 + m * 16 + l4 * 4 + g;
                float v = acc[m][n][g] + bcol[n];
                if (row < NT) { ls[n] += v; lq[n] += v * v; }
                if (row < store_n)
                    outp[(size_t)row * HD + wc * 64 + n * 16 + r15] = __float2bfloat16(v);
            }
    int part = (blockIdx.x & 31) * 256;
#pragma unroll
    for (int n = 0; n < 4; n++) {
        float s = ls[n], q2 = lq[n];
        s  += __shfl_xor(s, 16);  s  += __shfl_xor(s, 32);
        q2 += __shfl_xor(q2, 16); q2 += __shfl_xor(q2, 32);
        if (l4 == 0) {
            int c = wc * 64 + n * 16 + r15;
            atomicAdd(&spart[part + c], s);
            atomicAdd(&spart[part + 128 + c], q2);
        }
    }
}

// ---------------- BN finalize: reduce 32 partials -> per-column scale/shift ----------------
__global__ void k_fin(const float* __restrict__ sp, const float* __restrict__ g,
                      const float* __restrict__ be, float* __restrict__ ssout) {
    int j = threadIdx.x;   // 128
    float m = 0.f, q = 0.f;
    for (int i = 0; i < 32; i++) { m += sp[i * 256 + j]; q += sp[i * 256 + 128 + j]; }
    m *= (1.f / (float)NT);
    q = q * (1.f / (float)NT) - m * m;
    float s = g[j] * rsqrtf(q + 1e-5f);
    ssout[j] = s;
    ssout[HD + j] = be[j] - m * s;
}

// ---------------- Final: out = (relu(bn(raw2)) + x)[:NU] @ Wout^T + bout ----------------
__global__ __launch_bounds__(256) void k_out(const bf16* __restrict__ r2, const float* __restrict__ ss,
                                             const bf16* __restrict__ x, const float* __restrict__ wout,
                                             const float* __restrict__ bout, float* __restrict__ outp) {
    int lane = threadIdx.x & 63;
    int wid = (blockIdx.x * blockDim.x + threadIdx.x) >> 6;
    int nwv = (gridDim.x * blockDim.x) >> 6;
    int j0 = lane * 2;
    float s0 = ss[j0],       s1 = ss[j0 + 1];
    float t0 = ss[HD + j0],  t1 = ss[HD + j0 + 1];
    float w0 = wout[j0], w1 = wout[j0 + 1];
    float bo = bout[0];
    for (int r = wid; r < NUU; r += nwv) {
        unsigned ua = *(const unsigned*)(r2 + (size_t)r * HD + j0);
        unsigned ux = *(const unsigned*)(x + (size_t)r * HD + j0);
        float h0 = fmaxf(fmaf(bflo(ua), s0, t0), 0.f) + bflo(ux);
        float h1 = fmaxf(fmaf(bfhi(ua), s1, t1), 0.f) + bfhi(ux);
        float acc = h0 * w0 + h1 * w1;
#pragma unroll
        for (int off = 32; off; off >>= 1) acc += __shfl_down(acc, off);
        if (lane == 0) outp[r] = acc + bo;
    }
}

extern "C" void kernel_launch(void* const* d_in, const int* in_sizes, int n_in,
                              void* d_out, int out_size, void* d_ws, size_t ws_size,
                              hipStream_t stream) {
    const float* x_u = (const float*)d_in[0];
    const float* x_p = (const float*)d_in[1];
    const int*   ei  = (const int*)d_in[2];
    const float* W_u = (const float*)d_in[3];
    const float* b_u = (const float*)d_in[4];
    const float* W_p = (const float*)d_in[5];
    const float* b_p = (const float*)d_in[6];
    const float* W1l = (const float*)d_in[7];
    const float* b1l = (const float*)d_in[8];
    const float* W1r = (const float*)d_in[9];
    const float* g1  = (const float*)d_in[10];
    const float* be1 = (const float*)d_in[11];
    const float* W2l = (const float*)d_in[12];
    const float* b2l = (const float*)d_in[13];
    const float* W2r = (const float*)d_in[14];
    const float* g2  = (const float*)d_in[15];
    const float* be2 = (const float*)d_in[16];
    const float* Wout = (const float*)d_in[17];
    const float* bout = (const float*)d_in[18];

    float* out = (float*)d_out;

    if (ws_size < WS_NEED) {   // diagnostic fallback (should not trigger)
        k_zero<<<512, 256, 0, stream>>>((int*)d_out, out_size);
        return;
    }

    char* ws = (char*)d_ws;
    bf16* X      = (bf16*)(ws + X_OFF);
    bf16* R1     = (bf16*)(ws + R1_OFF);
    bf16* R2     = (bf16*)(ws + R2_OFF);
    int*  cnt    = (int*)(ws + CNT_OFF);
    float* spart = (float*)(ws + SPART_OFF);
    float* ssbuf = (float*)(ws + SS_OFF);
    int*  rp     = (int*)(ws + RPTR_OFF);
    int*  bsum   = (int*)(ws + BSUM_OFF);
    bf16* Bmat   = (bf16*)(ws + BMAT_OFF);
    int*  col    = (int*)(ws + COL_OFF);

    // Zero cnt + spart + ss (contiguous: 266,896 ints)
    k_zero<<<1043, 256, 0, stream>>>(cnt, 266896);
    k_wcvt<<<352, 256, 0, stream>>>(W1l, W1r, W2l, W2r, W_u, W_p, Bmat);

    // CSR build
    k_count<<<1024, 256, 0, stream>>>(ei, cnt);
    k_scan1<<<NBLK_SCAN, 256, 0, stream>>>(cnt, bsum);
    k_scan2<<<1, 1024, 0, stream>>>(bsum);
    k_scan3<<<NBLK_SCAN, 256, 0, stream>>>(cnt, bsum, rp);
    k_zero<<<977, 256, 0, stream>>>(cnt, NT);          // reuse cnt as fill
    k_fill<<<1024, 256, 0, stream>>>(ei, rp, cnt, col);

    // Projections -> X (bf16), MFMA with zero-padded K
    k_projm<100, 128><<<1563, 256, 0, stream>>>(x_u, Bmat + 65536, b_u, X, NUU, 0);
    k_projm<50, 64><<<391, 256, 0, stream>>>(x_p, Bmat + 81920, b_p, X, NPP, NUU);

    // Layer 1: X -> R1 (+stats1)
    k_gemm<false><<<1954, 256, 0, stream>>>(X, nullptr, rp, col, Bmat, b1l, R1, spart, NT);
    k_fin<<<1, 128, 0, stream>>>(spart, g1, be1, ssbuf);

    // Layer 2: f(R1) -> R2 (+stats2), BN1+relu folded into gather and A2 loads
    k_gemm<true><<<1954, 256, 0, stream>>>(R1, ssbuf, rp, col, Bmat + 32768, b2l, R2, spart + 8192, NUU);
    k_fin<<<1, 128, 0, stream>>>(spart + 8192, g2, be2, ssbuf + 256);

    // Output
    k_out<<<2048, 256, 0, stream>>>(R2, ssbuf + 256, X, Wout, bout, out);
}

// Round 5
// 452.597 us; speedup vs baseline: 14.4031x; 1.0272x over previous
//
#include <hip/hip_runtime.h>
#include <hip/hip_bf16.h>
#include <cstdint>
#include <cstddef>

// Problem constants
#define NT   250000      // total nodes
#define NUU  200000      // users
#define NPP  50000       // products
#define EG   500000      // directed edges
#define E2   1000000     // doubled (undirected)
#define HD   128
#define NBLK_SCAN 977    // ceil(NT/256)
#define NTILES 1954      // ceil(NT/128)

// Workspace layout (bytes) — total 185,451,728 (< proven-available 186,208,008)
#define X_OFF     0ull            // X  [NT*HD] bf16 = 64,000,000
#define R1_OFF    64000000ull     // R1 [NT*HD] bf16 = 64,000,000
#define R2_OFF    128000000ull    // R2 [NUU*HD] bf16 = 51,200,000
#define CNT_OFF   179200000ull    // cnt [NT] i32 (reused as fill) = 1,000,000
#define SPART_OFF 180200000ull    // stats partials 2 layers x 32 x 256 f32 = 65,536
#define SS_OFF    180265536ull    // ss1|ss2: 2 x 256 f32 = 2,048
#define RPTR_OFF  180267584ull    // row_ptr [NT+1] i32 = 1,000,004
#define BSUM_OFF  181267588ull    // block sums [977] i32 = 3,908
#define BMAT_OFF  181271504ull    // bf16 weights: L1[128][256] L2[128][256] PU[128][128] PP[128][64]
#define COL_OFF   181451728ull    // col [E2] i32 = 4,000,000
#define WS_NEED   185451728ull

typedef __hip_bfloat16 bf16;
typedef __attribute__((ext_vector_type(8))) short short8v;
typedef __attribute__((ext_vector_type(4))) float f32x4;

__device__ inline float bflo(unsigned u) { return __builtin_bit_cast(float, u << 16); }
__device__ inline float bfhi(unsigned u) { return __builtin_bit_cast(float, u & 0xffff0000u); }
__device__ inline float b2f(short s) { return __builtin_bit_cast(float, ((unsigned)(unsigned short)s) << 16); }
__device__ inline unsigned short f2bf(float f) { return __builtin_bit_cast(unsigned short, __float2bfloat16(f)); }

__global__ __launch_bounds__(256) void k_zero(int* __restrict__ p, int n) {
    for (int i = blockIdx.x * 256 + threadIdx.x; i < n; i += gridDim.x * 256) p[i] = 0;
}

// ---------------- CSR build ----------------
__global__ __launch_bounds__(256) void k_count(const int* __restrict__ ei, int* __restrict__ cnt) {
    for (int e = blockIdx.x * 256 + threadIdx.x; e < E2; e += gridDim.x * 256) {
        int d = (e < EG) ? ei[e + EG] : ei[e - EG];
        atomicAdd(&cnt[d], 1);
    }
}

__global__ __launch_bounds__(256) void k_scan1(const int* __restrict__ cnt, int* __restrict__ bsum) {
    __shared__ int lds[256];
    int i = blockIdx.x * 256 + threadIdx.x;
    int v = (i < NT) ? cnt[i] : 0;
    lds[threadIdx.x] = v; __syncthreads();
    for (int s = 128; s > 0; s >>= 1) {
        if (threadIdx.x < s) lds[threadIdx.x] += lds[threadIdx.x + s];
        __syncthreads();
    }
    if (threadIdx.x == 0) bsum[blockIdx.x] = lds[0];
}

__global__ __launch_bounds__(1024) void k_scan2(int* __restrict__ bsum) {
    __shared__ int lds[1024];
    int i = threadIdx.x;
    int v = (i < NBLK_SCAN) ? bsum[i] : 0;
    lds[i] = v; __syncthreads();
    for (int off = 1; off < 1024; off <<= 1) {
        int t = (i >= off) ? lds[i - off] : 0;
        __syncthreads();
        lds[i] += t;
        __syncthreads();
    }
    if (i < NBLK_SCAN) bsum[i] = lds[i] - v;   // exclusive
}

__global__ __launch_bounds__(256) void k_scan3(const int* __restrict__ cnt, const int* __restrict__ bsum,
                                               int* __restrict__ rp) {
    __shared__ int lds[256];
    int i = blockIdx.x * 256 + threadIdx.x;
    int v = (i < NT) ? cnt[i] : 0;
    lds[threadIdx.x] = v; __syncthreads();
    for (int off = 1; off < 256; off <<= 1) {
        int t = (threadIdx.x >= off) ? lds[threadIdx.x - off] : 0;
        __syncthreads();
        lds[threadIdx.x] += t;
        __syncthreads();
    }
    if (i < NT) rp[i] = bsum[blockIdx.x] + lds[threadIdx.x] - v;
    if (i == 0 && blockIdx.x == 0) rp[NT] = E2;
}

__global__ __launch_bounds__(256) void k_fill(const int* __restrict__ ei, const int* __restrict__ rp,
                                              int* __restrict__ fill, int* __restrict__ col) {
    for (int e = blockIdx.x * 256 + threadIdx.x; e < E2; e += gridDim.x * 256) {
        int s = ei[e];
        int d = (e < EG) ? ei[e + EG] : ei[e - EG];
        int slot = rp[d] + atomicAdd(&fill[d], 1);
        col[slot] = s;
    }
}

// ---------------- Weight conversion: fp32 -> bf16, stacked/padded ----------------
__global__ __launch_bounds__(256) void k_wcvt(const float* __restrict__ W1l, const float* __restrict__ W1r,
                                              const float* __restrict__ W2l, const float* __restrict__ W2r,
                                              const float* __restrict__ Wu, const float* __restrict__ Wp,
                                              bf16* __restrict__ B) {
    int i = blockIdx.x * 256 + threadIdx.x;
    if (i < 65536) {
        int layer = i >> 15, rem = i & 32767, o = rem >> 8, k = rem & 255;
        const float* W = layer ? ((k < 128) ? W2l : W2r) : ((k < 128) ? W1l : W1r);
        B[i] = __float2bfloat16(W[o * 128 + (k & 127)]);
    } else if (i < 81920) {
        int rem = i - 65536, o = rem >> 7, k = rem & 127;
        B[i] = __float2bfloat16((k < 100) ? Wu[o * 100 + k] : 0.f);
    } else if (i < 90112) {
        int rem = i - 81920, o = rem >> 6, k = rem & 63;
        B[i] = __float2bfloat16((k < 50) ? Wp[o * 50 + k] : 0.f);
    }
}

// ---------------- MFMA projection: X = relu(in @ Wp^T + b), K zero-padded ----------------
template<int DIN, int KPAD>
__global__ __launch_bounds__(256) void k_projm(const float* __restrict__ in, const bf16* __restrict__ Bp,
                                               const float* __restrict__ bias, bf16* __restrict__ outp,
                                               int nrows, int rowbase) {
    const int lane = threadIdx.x & 63;
    const int wid = threadIdx.x >> 6;
    const int wr = wid >> 1, wc = wid & 1;
    const int r15 = lane & 15, l4 = lane >> 4;
    const int tb = blockIdx.x * 128;
    constexpr int NKS = KPAD / 32;

    f32x4 acc[4][4] = {};
#pragma unroll
    for (int ks = 0; ks < NKS; ks++) {
        int kk = ks * 32 + l4 * 8;
        short8v a[4], b[4];
#pragma unroll
        for (int m = 0; m < 4; m++) {
            int r = tb + wr * 64 + m * 16 + r15;
            if (r > nrows - 1) r = nrows - 1;
            const float* src = in + (size_t)r * DIN + kk;
            short8v v;
            if (ks * 32 + 32 <= DIN) {   // compile-time per unrolled ks: fully in-bounds
                const float2* s2 = (const float2*)src;
                float2 f0 = s2[0], f1 = s2[1], f2 = s2[2], f3 = s2[3];
                v[0] = (short)f2bf(f0.x); v[1] = (short)f2bf(f0.y);
                v[2] = (short)f2bf(f1.x); v[3] = (short)f2bf(f1.y);
                v[4] = (short)f2bf(f2.x); v[5] = (short)f2bf(f2.y);
                v[6] = (short)f2bf(f3.x); v[7] = (short)f2bf(f3.y);
            } else {
#pragma unroll
                for (int j = 0; j < 8; j++) {
                    float f = (kk + j < DIN) ? src[j] : 0.f;
                    v[j] = (short)f2bf(f);
                }
            }
            a[m] = v;
        }
#pragma unroll
        for (int n = 0; n < 4; n++) {
            int c = wc * 64 + n * 16 + r15;
            b[n] = *(const short8v*)(Bp + (size_t)c * KPAD + kk);
        }
#pragma unroll
        for (int m = 0; m < 4; m++)
#pragma unroll
            for (int n = 0; n < 4; n++)
                acc[m][n] = __builtin_amdgcn_mfma_f32_16x16x32_bf16(a[m], b[n], acc[m][n], 0, 0, 0);
    }
    float bcol[4];
#pragma unroll
    for (int n = 0; n < 4; n++) bcol[n] = bias[wc * 64 + n * 16 + r15];
#pragma unroll
    for (int m = 0; m < 4; m++)
#pragma unroll
        for (int n = 0; n < 4; n++)
#pragma unroll
            for (int g = 0; g < 4; g++) {
                int row = tb + wr * 64 + m * 16 + l4 * 4 + g;
                if (row < nrows) {
                    float v = fmaxf(acc[m][n][g] + bcol[n], 0.f);
                    outp[(size_t)(rowbase + row) * HD + wc * 64 + n * 16 + r15] = __float2bfloat16(v);
                }
            }
}

// ---------------- Fused SAGE layer ----------------
// Phase A: pair-node gather — each 16-lane group runs 2 independent nodes (8 chains/wave),
//          masked 4-wide edge batches, rp prefetched via shfl. Tiles remapped for load balance.
// Phase B: K=256 MFMA; ks 0..3 from swizzled LDS mean tile, ks 4..7 own rows (norm on the fly).
template<bool NORM>
__global__ __launch_bounds__(256) void k_gemm(const bf16* __restrict__ hin, const float* __restrict__ ssv,
                                              const int* __restrict__ rp, const int* __restrict__ col,
                                              const bf16* __restrict__ Bmat, const float* __restrict__ blv,
                                              bf16* __restrict__ outp, float* __restrict__ spart,
                                              int store_n) {
    // Load-balance remap: interleave product tiles (1563..1953) 1-in-5 with user tiles.
    int g = blockIdx.x / 5, pos = blockIdx.x % 5;
    int tile = (pos < 4) ? (g * 4 + pos) : (1563 + g);
    if (pos < 4 && tile > 1562) return;   // only (g=390,pos=3)

    __shared__ unsigned int mrow[8192];   // 128 rows x 128 bf16, byte ^= (row&7)<<4 swizzle
    const int tid = threadIdx.x;
    const int lane = tid & 63;
    const int wid = tid >> 6;
    const int g16 = lane >> 4, l16 = lane & 15;
    const int tb = tile * 128;
    const int wnb = wid * 32;             // wave's node-local base
    const int fo = l16 * 8;               // feature offset for this lane

    // Per-lane BN fold constants for features fo..fo+7 (gather path)
    float sv[8], tv[8];
    if (NORM) {
#pragma unroll
        for (int j = 0; j < 8; j++) { sv[j] = ssv[fo + j]; tv[j] = ssv[HD + fo + j]; }
    }

    // Prefetch rp for the wave's 32 nodes (+1) in one coalesced load
    int rpv = 0;
    if (lane <= 32) rpv = rp[min(tb + wnb + lane, NT)];

    // ---- Phase A: 4 rounds x 8 nodes (2 per 16-lane group) ----
    for (int t = 0; t < 4; t++) {
        int nlA = wnb + t * 8 + g16;
        int nlB = nlA + 4;
        int a0 = __shfl(rpv, t * 8 + g16),     a1 = __shfl(rpv, t * 8 + g16 + 1);
        int b0 = __shfl(rpv, t * 8 + g16 + 4), b1 = __shfl(rpv, t * 8 + g16 + 5);
        if (tb + nlA >= NT) { a0 = 0; a1 = 0; }
        if (tb + nlB >= NT) { b0 = 0; b1 = 0; }
        float accA[8] = {}, accB[8] = {};
        int pA = a0, pB = b0;
        while (pA < a1 || pB < b1) {
            // col indices (clamped-safe), 8 independent chains
            int iA0 = (pA     < a1) ? pA     : 0;
            int iA1 = (pA + 1 < a1) ? pA + 1 : 0;
            int iA2 = (pA + 2 < a1) ? pA + 2 : 0;
            int iA3 = (pA + 3 < a1) ? pA + 3 : 0;
            int iB0 = (pB     < b1) ? pB     : 0;
            int iB1 = (pB + 1 < b1) ? pB + 1 : 0;
            int iB2 = (pB + 2 < b1) ? pB + 2 : 0;
            int iB3 = (pB + 3 < b1) ? pB + 3 : 0;
            int cA0 = col[iA0], cA1 = col[iA1], cA2 = col[iA2], cA3 = col[iA3];
            int cB0 = col[iB0], cB1 = col[iB1], cB2 = col[iB2], cB3 = col[iB3];
            short8v uA0 = *(const short8v*)(hin + (size_t)cA0 * HD + fo);
            short8v uA1 = *(const short8v*)(hin + (size_t)cA1 * HD + fo);
            short8v uA2 = *(const short8v*)(hin + (size_t)cA2 * HD + fo);
            short8v uA3 = *(const short8v*)(hin + (size_t)cA3 * HD + fo);
            short8v uB0 = *(const short8v*)(hin + (size_t)cB0 * HD + fo);
            short8v uB1 = *(const short8v*)(hin + (size_t)cB1 * HD + fo);
            short8v uB2 = *(const short8v*)(hin + (size_t)cB2 * HD + fo);
            short8v uB3 = *(const short8v*)(hin + (size_t)cB3 * HD + fo);
            float mA0 = (pA     < a1) ? 1.f : 0.f;
            float mA1 = (pA + 1 < a1) ? 1.f : 0.f;
            float mA2 = (pA + 2 < a1) ? 1.f : 0.f;
            float mA3 = (pA + 3 < a1) ? 1.f : 0.f;
            float mB0 = (pB     < b1) ? 1.f : 0.f;
            float mB1 = (pB + 1 < b1) ? 1.f : 0.f;
            float mB2 = (pB + 2 < b1) ? 1.f : 0.f;
            float mB3 = (pB + 3 < b1) ? 1.f : 0.f;
#pragma unroll
            for (int j = 0; j < 8; j++) {
                float vA0 = b2f(uA0[j]), vA1 = b2f(uA1[j]), vA2 = b2f(uA2[j]), vA3 = b2f(uA3[j]);
                float vB0 = b2f(uB0[j]), vB1 = b2f(uB1[j]), vB2 = b2f(uB2[j]), vB3 = b2f(uB3[j]);
                if (NORM) {
                    vA0 = fmaxf(fmaf(vA0, sv[j], tv[j]), 0.f);
                    vA1 = fmaxf(fmaf(vA1, sv[j], tv[j]), 0.f);
                    vA2 = fmaxf(fmaf(vA2, sv[j], tv[j]), 0.f);
                    vA3 = fmaxf(fmaf(vA3, sv[j], tv[j]), 0.f);
                    vB0 = fmaxf(fmaf(vB0, sv[j], tv[j]), 0.f);
                    vB1 = fmaxf(fmaf(vB1, sv[j], tv[j]), 0.f);
                    vB2 = fmaxf(fmaf(vB2, sv[j], tv[j]), 0.f);
                    vB3 = fmaxf(fmaf(vB3, sv[j], tv[j]), 0.f);
                }
                accA[j] += mA0 * vA0 + mA1 * vA1 + mA2 * vA2 + mA3 * vA3;
                accB[j] += mB0 * vB0 + mB1 * vB1 + mB2 * vB2 + mB3 * vB3;
            }
            pA += 4; pB += 4;
        }
        float invA = 1.f / (float)max(a1 - a0, 1);
        float invB = 1.f / (float)max(b1 - b0, 1);
        short8v wA, wB;
#pragma unroll
        for (int j = 0; j < 8; j++) {
            wA[j] = (short)f2bf(accA[j] * invA);
            wB[j] = (short)f2bf(accB[j] * invB);
        }
        int byteA = (nlA * 256 + l16 * 16) ^ ((nlA & 7) << 4);
        int byteB = (nlB * 256 + l16 * 16) ^ ((nlB & 7) << 4);
        *(short8v*)((char*)mrow + byteA) = wA;
        *(short8v*)((char*)mrow + byteB) = wB;
    }
    __syncthreads();

    // ---- Phase B: MFMA over K=256 ----
    const int wr = wid >> 1, wc = wid & 1;
    const int r15 = lane & 15, l4 = lane >> 4;
    f32x4 acc[4][4] = {};
#pragma unroll
    for (int ks = 0; ks < 8; ks++) {
        short8v a[4], b[4];
        if (ks < 4) {
            int kb = ks * 64 + l4 * 16;          // byte offset of k-slice within row
#pragma unroll
            for (int m = 0; m < 4; m++) {
                int r = wr * 64 + m * 16 + r15;
                int byte = (r * 256 + kb) ^ ((r & 7) << 4);
                a[m] = *(const short8v*)((const char*)mrow + byte);
            }
        } else {
            int k2 = (ks - 4) * 32 + l4 * 8;
            float sv2[8], tv2[8];
            if (NORM) {
#pragma unroll
                for (int j = 0; j < 8; j++) { sv2[j] = ssv[k2 + j]; tv2[j] = ssv[HD + k2 + j]; }
            }
#pragma unroll
            for (int m = 0; m < 4; m++) {
                int r = tb + wr * 64 + m * 16 + r15; if (r > NT - 1) r = NT - 1;
                short8v v = *(const short8v*)(hin + (size_t)r * HD + k2);
                if (NORM) {
#pragma unroll
                    for (int j = 0; j < 8; j++) {
                        float f = b2f(v[j]);
                        f = fmaxf(fmaf(f, sv2[j], tv2[j]), 0.f);
                        v[j] = (short)f2bf(f);
                    }
                }
                a[m] = v;
            }
        }
#pragma unroll
        for (int n = 0; n < 4; n++) {
            int c = wc * 64 + n * 16 + r15;
            b[n] = *(const short8v*)(Bmat + (size_t)c * 256 + ks * 32 + l4 * 8);
        }
#pragma unroll
        for (int m = 0; m < 4; m++)
#pragma unroll
            for (int n = 0; n < 4; n++)
                acc[m][n] = __builtin_amdgcn_mfma_f32_16x16x32_bf16(a[m], b[n], acc[m][n], 0, 0, 0);
    }

    // ---- Epilogue: bias, store, BN stats ----
    float bcol[4];
#pragma unroll
    for (int n = 0; n < 4; n++) bcol[n] = blv[wc * 64 + n * 16 + r15];
    float ls[4] = {0.f, 0.f, 0.f, 0.f}, lq[4] = {0.f, 0.f, 0.f, 0.f};
#pragma unroll
    for (int m = 0; m < 4; m++)
#pragma unroll
        for (int n = 0; n < 4; n++)
#pragma unroll
            for (int gg = 0; gg < 4; gg++) {
                int row = tb + wr * 64 + m * 16 + l4 * 4 + gg;
                float v = acc[m][n][gg] + bcol[n];
                if (row < NT) { ls[n] += v; lq[n] += v * v; }
                if (row < store_n)
                    outp[(size_t)row * HD + wc * 64 + n * 16 + r15] = __float2bfloat16(v);
            }
    int part = (tile & 31) * 256;
#pragma unroll
    for (int n = 0; n < 4; n++) {
        float s = ls[n], q2 = lq[n];
        s  += __shfl_xor(s, 16);  s  += __shfl_xor(s, 32);
        q2 += __shfl_xor(q2, 16); q2 += __shfl_xor(q2, 32);
        if (l4 == 0) {
            int c = wc * 64 + n * 16 + r15;
            atomicAdd(&spart[part + c], s);
            atomicAdd(&spart[part + 128 + c], q2);
        }
    }
}

// ---------------- BN finalize: reduce 32 partials -> per-column scale/shift ----------------
__global__ void k_fin(const float* __restrict__ sp, const float* __restrict__ g,
                      const float* __restrict__ be, float* __restrict__ ssout) {
    int j = threadIdx.x;   // 128
    float m = 0.f, q = 0.f;
    for (int i = 0; i < 32; i++) { m += sp[i * 256 + j]; q += sp[i * 256 + 128 + j]; }
    m *= (1.f / (float)NT);
    q = q * (1.f / (float)NT) - m * m;
    float s = g[j] * rsqrtf(q + 1e-5f);
    ssout[j] = s;
    ssout[HD + j] = be[j] - m * s;
}

// ---------------- Final: out = (relu(bn(raw2)) + x)[:NU] @ Wout^T + bout ----------------
__global__ __launch_bounds__(256) void k_out(const bf16* __restrict__ r2, const float* __restrict__ ss,
                                             const bf16* __restrict__ x, const float* __restrict__ wout,
                                             const float* __restrict__ bout, float* __restrict__ outp) {
    int lane = threadIdx.x & 63;
    int wid = (blockIdx.x * blockDim.x + threadIdx.x) >> 6;
    int nwv = (gridDim.x * blockDim.x) >> 6;
    int j0 = lane * 2;
    float s0 = ss[j0],       s1 = ss[j0 + 1];
    float t0 = ss[HD + j0],  t1 = ss[HD + j0 + 1];
    float w0 = wout[j0], w1 = wout[j0 + 1];
    float bo = bout[0];
    for (int r = wid; r < NUU; r += nwv) {
        unsigned ua = *(const unsigned*)(r2 + (size_t)r * HD + j0);
        unsigned ux = *(const unsigned*)(x + (size_t)r * HD + j0);
        float h0 = fmaxf(fmaf(bflo(ua), s0, t0), 0.f) + bflo(ux);
        float h1 = fmaxf(fmaf(bfhi(ua), s1, t1), 0.f) + bfhi(ux);
        float acc = h0 * w0 + h1 * w1;
#pragma unroll
        for (int off = 32; off; off >>= 1) acc += __shfl_down(acc, off);
        if (lane == 0) outp[r] = acc + bo;
    }
}

extern "C" void kernel_launch(void* const* d_in, const int* in_sizes, int n_in,
                              void* d_out, int out_size, void* d_ws, size_t ws_size,
                              hipStream_t stream) {
    const float* x_u = (const float*)d_in[0];
    const float* x_p = (const float*)d_in[1];
    const int*   ei  = (const int*)d_in[2];
    const float* W_u = (const float*)d_in[3];
    const float* b_u = (const float*)d_in[4];
    const float* W_p = (const float*)d_in[5];
    const float* b_p = (const float*)d_in[6];
    const float* W1l = (const float*)d_in[7];
    const float* b1l = (const float*)d_in[8];
    const float* W1r = (const float*)d_in[9];
    const float* g1  = (const float*)d_in[10];
    const float* be1 = (const float*)d_in[11];
    const float* W2l = (const float*)d_in[12];
    const float* b2l = (const float*)d_in[13];
    const float* W2r = (const float*)d_in[14];
    const float* g2  = (const float*)d_in[15];
    const float* be2 = (const float*)d_in[16];
    const float* Wout = (const float*)d_in[17];
    const float* bout = (const float*)d_in[18];

    float* out = (float*)d_out;

    if (ws_size < WS_NEED) {   // diagnostic fallback (should not trigger)
        k_zero<<<512, 256, 0, stream>>>((int*)d_out, out_size);
        return;
    }

    char* ws = (char*)d_ws;
    bf16* X      = (bf16*)(ws + X_OFF);
    bf16* R1     = (bf16*)(ws + R1_OFF);
    bf16* R2     = (bf16*)(ws + R2_OFF);
    int*  cnt    = (int*)(ws + CNT_OFF);
    float* spart = (float*)(ws + SPART_OFF);
    float* ssbuf = (float*)(ws + SS_OFF);
    int*  rp     = (int*)(ws + RPTR_OFF);
    int*  bsum   = (int*)(ws + BSUM_OFF);
    bf16* Bmat   = (bf16*)(ws + BMAT_OFF);
    int*  col    = (int*)(ws + COL_OFF);

    // Zero cnt + spart + ss (contiguous: 266,896 ints)
    k_zero<<<1043, 256, 0, stream>>>(cnt, 266896);
    k_wcvt<<<352, 256, 0, stream>>>(W1l, W1r, W2l, W2r, W_u, W_p, Bmat);

    // CSR build
    k_count<<<1024, 256, 0, stream>>>(ei, cnt);
    k_scan1<<<NBLK_SCAN, 256, 0, stream>>>(cnt, bsum);
    k_scan2<<<1, 1024, 0, stream>>>(bsum);
    k_scan3<<<NBLK_SCAN, 256, 0, stream>>>(cnt, bsum, rp);
    k_zero<<<977, 256, 0, stream>>>(cnt, NT);          // reuse cnt as fill
    k_fill<<<1024, 256, 0, stream>>>(ei, rp, cnt, col);

    // Projections -> X (bf16), MFMA with zero-padded K
    k_projm<100, 128><<<1563, 256, 0, stream>>>(x_u, Bmat + 65536, b_u, X, NUU, 0);
    k_projm<50, 64><<<391, 256, 0, stream>>>(x_p, Bmat + 81920, b_p, X, NPP, NUU);

    // Layer 1: X -> R1 (+stats1)    (grid 1955 = 391 groups x 5, one no-op block)
    k_gemm<false><<<1955, 256, 0, stream>>>(X, nullptr, rp, col, Bmat, b1l, R1, spart, NT);
    k_fin<<<1, 128, 0, stream>>>(spart, g1, be1, ssbuf);

    // Layer 2: f(R1) -> R2 (+stats2), BN1+relu folded into gather and A2 loads
    k_gemm<true><<<1955, 256, 0, stream>>>(R1, ssbuf, rp, col, Bmat + 32768, b2l, R2, spart + 8192, NUU);
    k_fin<<<1, 128, 0, stream>>>(spart + 8192, g2, be2, ssbuf + 256);

    // Output
    k_out<<<2048, 256, 0, stream>>>(R2, ssbuf + 256, X, Wout, bout, out);
}